// Round 3
// baseline (769.781 us; speedup 1.0000x reference)
//
#include <hip/hip_runtime.h>
#include <math.h>

#define NB 64
#define NN 4096
#define NF 256
#define NC 10
#define NSPLIT 16
#define CH 256            // rows per split
#define LW 263            // LDS tile pitch (floats) — odd → conflict-free transposed reads
#define USLOTS 4096       // k_uniq hash slots (12-bit)

// ---------------------------------------------------------------- K1: streaming stats + transpose
// v4: writer-side stats + register-prefetch pipeline.
//   phase 1: clean (NaN->0, -0->+0) prefetched tile; accumulate ALL stats from the
//            registers (wave = one row → y is wave-uniform: 1 readlane + 1 scalar
//            switch per 4-element group); ds_write into skewed LDS tile.
//   phase 2: issue next tile's 8 float4 loads FIRST, then transpose write-out to XT.
//   No second LDS read for stats (v3's phase 2c is gone: 32 ds_read + 32 readlane +
//   32 scalar switches per thread-tile removed).
//   End: cross-wave reduction via skewed red[f*16 + (f>>2) + s] — banks (l+c)%32
//   for writers / 2-way for readers → conflict-free (R0's 64-way conflict fixed).
__global__ __launch_bounds__(256, 3) void k_stats(const float* __restrict__ X,
                                                  const int* __restrict__ Y,
                                                  unsigned* __restrict__ XT,
                                                  float* __restrict__ P) {
  __shared__ unsigned ldsT[32 * LW];  // 33,664 B -> 4 blocks/CU
  const int bi = blockIdx.x;
  const int b = bi >> 4, sp = bi & 15;
  const int t = threadIdx.x;
  const int w = t >> 6, l = t & 63;
  const int n0 = sp * CH;
  const float4* Xv = (const float4*)X;

  // Y chunk preload: lane l holds rows n0+{l, 64+l, 128+l, 192+l}
  const int y0 = Y[b * NN + n0 + l];
  const int y1 = Y[b * NN + n0 + 64 + l];
  const int y2 = Y[b * NN + n0 + 128 + l];
  const int y3 = Y[b * NN + n0 + 192 + l];

  // writer-side accumulators: lane l owns features 4l..4l+3, rows ≡ w (mod 4)
  float s1[4] = {0, 0, 0, 0}, s2[4] = {0, 0, 0, 0}, sab[4] = {0, 0, 0, 0};
  float mab[4] = {0, 0, 0, 0}, nanc[4] = {0, 0, 0, 0};
  float cls[NC][4] = {};
  const int colbase = 4 * l + (l >> 3);

#define ADD4(c) do { cls[c][0]+=cv[0]; cls[c][1]+=cv[1]; cls[c][2]+=cv[2]; cls[c][3]+=cv[3]; } while(0)

  float4 pf[8];
#pragma unroll
  for (int it = 0; it < 8; ++it) {  // prime tile 0
    const int n = n0 + it * 4 + w;
    pf[it] = Xv[(size_t)(b * NN + n) * (NF / 4) + l];
  }

  for (int tile = 0; tile < 8; ++tile) {
    const int kk = tile >> 1;
    const int yl = (kk & 2) ? ((kk & 1) ? y3 : y2) : ((kk & 1) ? y1 : y0);
    const int lbase = (tile & 1) * 32 + w;   // wave-uniform
    // ---- phase 1: clean + stats + LDS write (consumes pf)
#pragma unroll
    for (int it = 0; it < 8; ++it) {
      const float v[4] = {pf[it].x, pf[it].y, pf[it].z, pf[it].w};
      float cv[4];
#pragma unroll
      for (int q = 0; q < 4; ++q) {
        float c = v[q];
        if (c != c) { nanc[q] += 1.f; c = 0.f; }           // nan_to_num(nan=0)
        cv[q] = c;
        s1[q] += c;
        s2[q] = fmaf(c, c, s2[q]);
        const float a = fabsf(c);
        sab[q] += a;
        mab[q] = fmaxf(mab[q], a);
      }
      const int ys = __builtin_amdgcn_readlane(yl, lbase + it * 4);  // wave-uniform
      switch (ys) {
        case 0: ADD4(0); break; case 1: ADD4(1); break;
        case 2: ADD4(2); break; case 3: ADD4(3); break;
        case 4: ADD4(4); break; case 5: ADD4(5); break;
        case 6: ADD4(6); break; case 7: ADD4(7); break;
        case 8: ADD4(8); break; case 9: ADD4(9); break;
        default: break;
      }
      const int lb = (it * 4 + w) * LW + colbase;
      ldsT[lb + 0] = (cv[0] == 0.f) ? 0u : __float_as_uint(cv[0]);  // -0 -> +0
      ldsT[lb + 1] = (cv[1] == 0.f) ? 0u : __float_as_uint(cv[1]);
      ldsT[lb + 2] = (cv[2] == 0.f) ? 0u : __float_as_uint(cv[2]);
      ldsT[lb + 3] = (cv[3] == 0.f) ? 0u : __float_as_uint(cv[3]);
    }
    __syncthreads();

    // ---- phase 2a: prefetch next tile into regs (in flight across everything below)
    if (tile < 7) {
#pragma unroll
      for (int it = 0; it < 8; ++it) {
        const int n = n0 + (tile + 1) * 32 + it * 4 + w;
        pf[it] = Xv[(size_t)(b * NN + n) * (NF / 4) + l];
      }
    }

    // ---- phase 2b: transposed write-out (8 threads cooperate per feature → 128B segments)
#pragma unroll
    for (int j = 0; j < 8; ++j) {
      const int idx = t + 256 * j;
      const int f = idx >> 3, rr4 = idx & 7;
      const int fo = f + (f >> 5);
      uint4 o;
      o.x = ldsT[(rr4 * 4 + 0) * LW + fo];
      o.y = ldsT[(rr4 * 4 + 1) * LW + fo];
      o.z = ldsT[(rr4 * 4 + 2) * LW + fo];
      o.w = ldsT[(rr4 * 4 + 3) * LW + fo];
      ((uint4*)(XT + (size_t)(b * NF + f) * NN + n0 + tile * 32))[rr4] = o;
    }
    __syncthreads();
  }
#undef ADD4

  // cross-wave reduction via skewed LDS: red[f*16 + (f>>2) + s]
  float* red = (float*)ldsT;
  for (int ph = 0; ph < 4; ++ph) {
    if (w == ph) {
#pragma unroll
      for (int ff = 0; ff < 4; ++ff) {
        const int f = 4 * l + ff;
        const int base = f * 16 + (f >> 2);
        float vals[15];
        vals[0] = s1[ff]; vals[1] = s2[ff]; vals[2] = sab[ff];
        vals[3] = mab[ff]; vals[4] = nanc[ff];
#pragma unroll
        for (int c = 0; c < NC; ++c) vals[5 + c] = cls[c][ff];
        if (ph == 0) {
#pragma unroll
          for (int s = 0; s < 15; ++s) red[base + s] = vals[s];
          red[base + 15] = 0.f;
        } else {
          red[base + 0] += vals[0];
          red[base + 1] += vals[1];
          red[base + 2] += vals[2];
          red[base + 3] = fmaxf(red[base + 3], vals[3]);
          red[base + 4] += vals[4];
#pragma unroll
          for (int c = 0; c < NC; ++c) red[base + 5 + c] += vals[5 + c];
        }
      }
    }
    __syncthreads();
  }
  // write P: thread t owns feature t (2-way bank reads, coalesced stores)
  const int rb = t * 16 + (t >> 2);
  float vals[16];
#pragma unroll
  for (int s = 0; s < 16; ++s) vals[s] = red[rb + s];
  float4* Pv = (float4*)(P + ((size_t)(b * NSPLIT + sp) * NF + t) * 16);
  Pv[0] = *(float4*)&vals[0];
  Pv[1] = *(float4*)&vals[4];
  Pv[2] = *(float4*)&vals[8];
  Pv[3] = *(float4*)&vals[12];
}

// ---------------------------------------------------------------- K3: exact distinct count per column
// v5: claimant-tag dedup — no table scan, no clears, no initialization.
//   Per level: (1) pending keys write-race tab[h]=key. (2) barrier; copies whose
//   readback matches write a 16-bit tag (tid*16+q) to tag[h]; losers rehash.
//   (3) barrier; tag readback == own tag → claim one distinct value.
__global__ __launch_bounds__(256) void k_uniq(const unsigned* __restrict__ XT,
                                              unsigned* __restrict__ uniq) {
  __shared__ unsigned tab[USLOTS];          // 16,384 B — value write-race table
  __shared__ unsigned short tag[USLOTS];    //  8,192 B — claimant tags
  const int t = threadIdx.x;
  const size_t base = (size_t)blockIdx.x * NN;

  const uint4* Xv = (const uint4*)(XT + base);
  uint4 kv0 = Xv[t], kv1 = Xv[256 + t], kv2 = Xv[512 + t], kv3 = Xv[768 + t];

  unsigned key[16] = {kv0.x, kv0.y, kv0.z, kv0.w, kv1.x, kv1.y, kv1.z, kv1.w,
                      kv2.x, kv2.y, kv2.z, kv2.w, kv3.x, kv3.y, kv3.z, kv3.w};
  unsigned h[16];
#pragma unroll
  for (int q = 0; q < 16; ++q) h[q] = (key[q] * 2654435761u) >> 20;  // 12 bits
  unsigned pend = 0xFFFFu;
  unsigned salt = 0x9E3779B9u;
  int cnt = 0;

  while (true) {
    // (1) value write-race (plain stores; racing word-writes resolve to one winner)
#pragma unroll
    for (int q = 0; q < 16; ++q)
      if (pend & (1u << q)) tab[h[q]] = key[q];
    __syncthreads();
    // (2) classify: matching copies stake a tag claim; losers rehash for next level
    unsigned match = 0;
#pragma unroll
    for (int q = 0; q < 16; ++q)
      if (pend & (1u << q)) {
        if (tab[h[q]] == key[q]) {
          match |= (1u << q);
          tag[h[q]] = (unsigned short)(t * 16 + q);
        } else {
          h[q] = ((key[q] ^ salt) * 2654435761u) >> 20;
        }
      }
    salt += 0x9E3779B9u;
    __syncthreads();
    // (3) claim: exactly one copy of each resolved value wins the tag race
#pragma unroll
    for (int q = 0; q < 16; ++q)
      if (match & (1u << q))
        cnt += (tag[h[q]] == (unsigned short)(t * 16 + q)) ? 1 : 0;
    pend &= ~match;
    if (__syncthreads_count(pend != 0) == 0) break;  // also orders claims vs next level
  }

  for (int off = 32; off; off >>= 1) cnt += __shfl_down(cnt, off, 64);
  // loop-exit barrier ordered all table traffic; reuse tab for cross-wave partials
  if ((t & 63) == 0) tab[t >> 6] = (unsigned)cnt;
  __syncthreads();
  if (t == 0) uniq[blockIdx.x] = tab[0] + tab[1] + tab[2] + tab[3];
}

// ---------------------------------------------------------------- K2: reduce partials → 6 stats
// also computes the per-batch class histogram (k_counts folded in): compare-chain
// per-thread counts + wave shuffle-reduce — no atomics.
__global__ __launch_bounds__(256) void k_finalize(const float* __restrict__ P,
                                                  const int* __restrict__ Y,
                                                  const unsigned* __restrict__ uniq,
                                                  float* __restrict__ stats6) {
  __shared__ float whist[4 * NC];
  const int b = blockIdx.x;          // 64 blocks == batches
  const int t = threadIdx.x;

  int cnt[NC];
#pragma unroll
  for (int c = 0; c < NC; ++c) cnt[c] = 0;
#pragma unroll
  for (int i = 0; i < 16; ++i) {
    const int y = Y[b * NN + 256 * i + t];
#pragma unroll
    for (int c = 0; c < NC; ++c) cnt[c] += (y == c) ? 1 : 0;
  }
#pragma unroll
  for (int c = 0; c < NC; ++c) {
    int v = cnt[c];
    for (int off = 32; off; off >>= 1) v += __shfl_down(v, off, 64);
    cnt[c] = v;
  }
  if ((t & 63) == 0) {
#pragma unroll
    for (int c = 0; c < NC; ++c) whist[(t >> 6) * NC + c] = (float)cnt[c];
  }
  __syncthreads();

  const int f = t;
  const int col = b * 256 + f;
  float acc[16];
#pragma unroll
  for (int i = 0; i < 16; ++i) acc[i] = 0.f;
  for (int sp = 0; sp < NSPLIT; ++sp) {
    const float4* p4 = (const float4*)(P + ((size_t)(b * NSPLIT + sp) * NF + f) * 16);
    float4 A = p4[0], B4 = p4[1], C4 = p4[2], D4 = p4[3];
    acc[0] += A.x; acc[1] += A.y; acc[2] += A.z; acc[3] = fmaxf(acc[3], A.w);
    acc[4] += B4.x; acc[5] += B4.y; acc[6] += B4.z; acc[7] += B4.w;
    acc[8] += C4.x; acc[9] += C4.y; acc[10] += C4.z; acc[11] += C4.w;
    acc[12] += D4.x; acc[13] += D4.y; acc[14] += D4.z;
  }
  const float invN = 1.f / (float)NN;
  const float mean = acc[0] * invN;
  float var = acc[1] * invN - mean * mean;
  if (var < 0.f) var = 0.f;
  const float meanabs = acc[2] * invN;
  const float maxabs = acc[3];
  const float miss = acc[4] * invN;
  const float uratio = (float)uniq[col] * invN;
  float btw = 0.f;
#pragma unroll
  for (int c = 0; c < NC; ++c) {
    const float cntc = whist[c] + whist[NC + c] + whist[2 * NC + c] + whist[3 * NC + c];
    const float m = acc[5 + c] / fmaxf(cntc, 1.f);
    const float d = m - mean;
    btw = fmaf(cntc * d, d, btw);
  }
  btw *= invN;  // counts.sum() == N
  const float target = btw / fmaxf(var, 1e-6f);
  float st[6] = {target, miss, uratio, var, meanabs, maxabs};
#pragma unroll
  for (int i = 0; i < 6; ++i)
    if (!(fabsf(st[i]) <= 3.4028235e38f)) st[i] = 0.f;  // nan_to_num(nan/±inf → 0)
#pragma unroll
  for (int i = 0; i < 6; ++i) stats6[(size_t)col * 6 + i] = st[i];
}

// ---------------------------------------------------------------- K4: MLP  gelu(stats@W1+b1)@W2+b2
__global__ __launch_bounds__(256) void k_mlp(const float* __restrict__ stats6,
                                             const float* __restrict__ W1,
                                             const float* __restrict__ b1,
                                             const float* __restrict__ W2,
                                             const float* __restrict__ b2,
                                             float* __restrict__ out) {
  __shared__ float w1s[6 * 64];
  __shared__ float b1s[64];
  __shared__ float w2s[64 * 128];
  __shared__ float b2s[128];
  __shared__ float sts[32 * 6];
  __shared__ float hs[64 * 36];  // pitch 36 keeps float4 reads 16B-aligned
  const int t = threadIdx.x;
  const int cb0 = blockIdx.x * 32;
  for (int i = t; i < 96; i += 256) ((float4*)w1s)[i] = ((const float4*)W1)[i];
  if (t < 64) b1s[t] = b1[t];
  for (int i = t; i < 2048; i += 256) ((float4*)w2s)[i] = ((const float4*)W2)[i];
  if (t < 128) b2s[t] = b2[t];
  if (t < 48) ((float4*)sts)[t] = ((const float4*)(stats6 + (size_t)cb0 * 6))[t];
  __syncthreads();

  const int k = t & 63, cg = t >> 6;
#pragma unroll
  for (int cc = 0; cc < 8; ++cc) {
    const int col = cg + 4 * cc;
    float pre = b1s[k];
#pragma unroll
    for (int s = 0; s < 6; ++s) pre = fmaf(sts[col * 6 + s], w1s[s * 64 + k], pre);
    const float h = 0.5f * pre * (1.f + erff(pre * 0.70710678118654752f));  // exact gelu
    hs[k * 36 + col] = h;
  }
  __syncthreads();

  const int j4 = (t & 31) * 4, c4 = (t >> 5) * 4;
  float4 a[4];
  const float4 bj = *(const float4*)&b2s[j4];
  a[0] = bj; a[1] = bj; a[2] = bj; a[3] = bj;
  for (int kk = 0; kk < 64; ++kk) {
    const float4 wv = *(const float4*)&w2s[kk * 128 + j4];
    const float4 hv = *(const float4*)&hs[kk * 36 + c4];
    const float hc[4] = {hv.x, hv.y, hv.z, hv.w};
#pragma unroll
    for (int ci = 0; ci < 4; ++ci) {
      a[ci].x = fmaf(hc[ci], wv.x, a[ci].x);
      a[ci].y = fmaf(hc[ci], wv.y, a[ci].y);
      a[ci].z = fmaf(hc[ci], wv.z, a[ci].z);
      a[ci].w = fmaf(hc[ci], wv.w, a[ci].w);
    }
  }
#pragma unroll
  for (int ci = 0; ci < 4; ++ci) {
    const int col = cb0 + c4 + ci;
    *(float4*)&out[(size_t)col * 128 + j4] = a[ci];
  }
}

// ---------------------------------------------------------------- launch
extern "C" void kernel_launch(void* const* d_in, const int* in_sizes, int n_in,
                              void* d_out, int out_size, void* d_ws, size_t ws_size,
                              hipStream_t stream) {
  const float* X = (const float*)d_in[0];
  const int* Y = (const int*)d_in[1];
  const float* W1 = (const float*)d_in[2];
  const float* b1 = (const float*)d_in[3];
  const float* W2 = (const float*)d_in[4];
  const float* b2 = (const float*)d_in[5];
  float* out = (float*)d_out;

  // workspace layout (~272.4 MiB)
  char* w = (char*)d_ws;
  unsigned* XT = (unsigned*)w;                          // 268,435,456 B  [B,F,N] cleaned bit patterns
  float* P = (float*)(w + 268435456ull);                //  16,777,216 B  partial stats [B,S,F,16]
  float* stats6 = (float*)(w + 285212672ull);           //     393,216 B  [16384,6]
  unsigned* uniq = (unsigned*)(w + 285608448ull);       //      65,536 B  [16384]

  k_stats<<<NB * NSPLIT, 256, 0, stream>>>(X, Y, XT, P);
  k_uniq<<<NB * NF, 256, 0, stream>>>(XT, uniq);
  k_finalize<<<NB, 256, 0, stream>>>(P, Y, uniq, stats6);
  k_mlp<<<512, 256, 0, stream>>>(stats6, W1, b1, W2, b2, out);
}

// Round 4
// 586.591 us; speedup vs baseline: 1.3123x; 1.3123x over previous
//
#include <hip/hip_runtime.h>
#include <math.h>

#define NB 64
#define NN 4096
#define NF 256
#define NC 10
#define NSPLIT 32
#define CH 128            // rows per split
#define USLOTS 4096       // k_uniq hash slots (12-bit)

// ---------------------------------------------------------------- K1: streaming stats + transpose
// v5: reader-side stats (R2 structure, VGPR ~64, no spill) + XOR-block LDS swizzle.
//   LDS tile: [32 rows][64 uint4 blocks], block B of row r stored at r*64 + (B ^ (r>>2)).
//     - phase-1 writes: one ds_write_b128/lane, row-uniform, distinct blocks → conflict-free
//     - transpose reads (word f of row R): R*256 + (((f>>2) ^ (R>>2))<<2 | (f&3)) → ≤2-way
//   Pitch 256 → LDS = 32,768 B exactly → 5 blocks/CU (was 33,664 B → 4).
//   NSPLIT 32 → grid 2048 = 8 blocks/CU: 5 resident + 3 backfill hide barrier bubbles.
__global__ __launch_bounds__(256) void k_stats(const float* __restrict__ X,
                                               const int* __restrict__ Y,
                                               unsigned* __restrict__ XT,
                                               float* __restrict__ P) {
  __shared__ unsigned ldsT[32 * 256];  // 32,768 B
  const int bi = blockIdx.x;
  const int b = bi >> 5, sp = bi & 31;
  const int t = threadIdx.x;
  const int w = t >> 6, l = t & 63;
  const int n0 = sp * CH;
  const float4* Xv = (const float4*)X;

  // Y chunk preload: lane l holds rows n0+l and n0+64+l
  const int y0 = Y[b * NN + n0 + l];
  const int y1 = Y[b * NN + n0 + 64 + l];

  // reader-side accumulators: thread t owns feature t
  float s1 = 0.f, s2 = 0.f, sab = 0.f, mab = 0.f;
  float cls[NC] = {};
  // writer-side NaN counts for features 4l..4l+3 over rows ≡ w (mod 4)
  float nanc4[4] = {0.f, 0.f, 0.f, 0.f};

  float4 pf[8];
#pragma unroll
  for (int it = 0; it < 8; ++it) {  // prime tile 0
    const int n = n0 + it * 4 + w;
    pf[it] = Xv[(size_t)(b * NN + n) * (NF / 4) + l];
  }

  for (int tile = 0; tile < 4; ++tile) {
    // ---- phase 1: clean (NaN->0, -0->+0) + one b128 LDS write per lane
#pragma unroll
    for (int it = 0; it < 8; ++it) {
      const int r = it * 4 + w;
      const float v[4] = {pf[it].x, pf[it].y, pf[it].z, pf[it].w};
      uint4 uv;
      unsigned ub[4];
#pragma unroll
      for (int q = 0; q < 4; ++q) {
        float c = v[q];
        if (c != c) { nanc4[q] += 1.f; c = 0.f; }          // nan_to_num(nan=0)
        ub[q] = (c == 0.f) ? 0u : __float_as_uint(c);      // -0 -> +0
      }
      uv.x = ub[0]; uv.y = ub[1]; uv.z = ub[2]; uv.w = ub[3];
      ((uint4*)ldsT)[r * 64 + (l ^ (r >> 2))] = uv;        // conflict-free b128
    }
    __syncthreads();

    // ---- phase 2a: prefetch next tile into regs (in flight across everything below)
    if (tile < 3) {
#pragma unroll
      for (int it = 0; it < 8; ++it) {
        const int n = n0 + (tile + 1) * 32 + it * 4 + w;
        pf[it] = Xv[(size_t)(b * NN + n) * (NF / 4) + l];
      }
    }

    // ---- phase 2b: transposed write-out (8 threads/feature → 128B coalesced segments)
#pragma unroll
    for (int j = 0; j < 8; ++j) {
      const int idx = t + 256 * j;
      const int f = idx >> 3, rr4 = idx & 7;
      const int colw = ((((f >> 2) ^ rr4) << 2) | (f & 3));  // R>>2 == rr4 for all 4 rows
      uint4 o;
      o.x = ldsT[(rr4 * 4 + 0) * 256 + colw];
      o.y = ldsT[(rr4 * 4 + 1) * 256 + colw];
      o.z = ldsT[(rr4 * 4 + 2) * 256 + colw];
      o.w = ldsT[(rr4 * 4 + 3) * 256 + colw];
      ((uint4*)(XT + (size_t)(b * NF + f) * NN + n0 + tile * 32))[rr4] = o;
    }

    // ---- phase 2c: stats for feature t over this tile's 32 rows (≤2-way reads)
    const int yl = (tile >> 1) ? y1 : y0;
    const int lbase = (tile & 1) * 32;
    const int ahi = t >> 2, a2 = t & 3;
#pragma unroll
    for (int r = 0; r < 32; ++r) {
      const float c = __uint_as_float(ldsT[r * 256 + (((ahi ^ (r >> 2)) << 2) | a2)]);
      const int y = __builtin_amdgcn_readlane(yl, lbase + r);  // wave-uniform
      s1 += c;
      s2 = fmaf(c, c, s2);
      const float a = fabsf(c);
      sab += a;
      mab = fmaxf(mab, a);
      switch (y) {
        case 0: cls[0] += c; break; case 1: cls[1] += c; break;
        case 2: cls[2] += c; break; case 3: cls[3] += c; break;
        case 4: cls[4] += c; break; case 5: cls[5] += c; break;
        case 6: cls[6] += c; break; case 7: cls[7] += c; break;
        case 8: cls[8] += c; break; case 9: cls[9] += c; break;
        default: break;
      }
    }
    __syncthreads();
  }

  // NaN-count redistribution (writer-side 4-feat counts -> reader-side feature t)
  float* nl = (float*)ldsT;
#pragma unroll
  for (int q = 0; q < 4; ++q) nl[w * 256 + 4 * l + q] = nanc4[q];
  __syncthreads();
  const float nanc = nl[t] + nl[256 + t] + nl[512 + t] + nl[768 + t];

  float vals[16];
  vals[0] = s1; vals[1] = s2; vals[2] = sab; vals[3] = mab; vals[4] = nanc;
#pragma unroll
  for (int c = 0; c < NC; ++c) vals[5 + c] = cls[c];
  vals[15] = 0.f;
  float4* Pv = (float4*)(P + ((size_t)(b * NSPLIT + sp) * NF + t) * 16);
  Pv[0] = *(float4*)&vals[0];
  Pv[1] = *(float4*)&vals[4];
  Pv[2] = *(float4*)&vals[8];
  Pv[3] = *(float4*)&vals[12];
}

// ---------------------------------------------------------------- K3: exact distinct count per column
// claimant-tag dedup — no table scan, no clears, no initialization.
//   Per level: (1) pending keys write-race tab[h]=key. (2) barrier; copies whose
//   readback matches write a 16-bit tag (tid*16+q) to tag[h]; losers rehash.
//   (3) barrier; tag readback == own tag → claim one distinct value.
__global__ __launch_bounds__(256) void k_uniq(const unsigned* __restrict__ XT,
                                              unsigned* __restrict__ uniq) {
  __shared__ unsigned tab[USLOTS];          // 16,384 B — value write-race table
  __shared__ unsigned short tag[USLOTS];    //  8,192 B — claimant tags
  const int t = threadIdx.x;
  const size_t base = (size_t)blockIdx.x * NN;

  const uint4* Xv = (const uint4*)(XT + base);
  uint4 kv0 = Xv[t], kv1 = Xv[256 + t], kv2 = Xv[512 + t], kv3 = Xv[768 + t];

  unsigned key[16] = {kv0.x, kv0.y, kv0.z, kv0.w, kv1.x, kv1.y, kv1.z, kv1.w,
                      kv2.x, kv2.y, kv2.z, kv2.w, kv3.x, kv3.y, kv3.z, kv3.w};
  unsigned h[16];
#pragma unroll
  for (int q = 0; q < 16; ++q) h[q] = (key[q] * 2654435761u) >> 20;  // 12 bits
  unsigned pend = 0xFFFFu;
  unsigned salt = 0x9E3779B9u;
  int cnt = 0;

  while (true) {
    // (1) value write-race (plain stores; racing word-writes resolve to one winner)
#pragma unroll
    for (int q = 0; q < 16; ++q)
      if (pend & (1u << q)) tab[h[q]] = key[q];
    __syncthreads();
    // (2) classify: matching copies stake a tag claim; losers rehash for next level
    unsigned match = 0;
#pragma unroll
    for (int q = 0; q < 16; ++q)
      if (pend & (1u << q)) {
        if (tab[h[q]] == key[q]) {
          match |= (1u << q);
          tag[h[q]] = (unsigned short)(t * 16 + q);
        } else {
          h[q] = ((key[q] ^ salt) * 2654435761u) >> 20;
        }
      }
    salt += 0x9E3779B9u;
    __syncthreads();
    // (3) claim: exactly one copy of each resolved value wins the tag race
#pragma unroll
    for (int q = 0; q < 16; ++q)
      if (match & (1u << q))
        cnt += (tag[h[q]] == (unsigned short)(t * 16 + q)) ? 1 : 0;
    pend &= ~match;
    if (__syncthreads_count(pend != 0) == 0) break;  // also orders claims vs next level
  }

  for (int off = 32; off; off >>= 1) cnt += __shfl_down(cnt, off, 64);
  // loop-exit barrier ordered all table traffic; reuse tab for cross-wave partials
  if ((t & 63) == 0) tab[t >> 6] = (unsigned)cnt;
  __syncthreads();
  if (t == 0) uniq[blockIdx.x] = tab[0] + tab[1] + tab[2] + tab[3];
}

// ---------------------------------------------------------------- K2: reduce partials → 6 stats
// also computes the per-batch class histogram (k_counts folded in): compare-chain
// per-thread counts + wave shuffle-reduce — no atomics.
__global__ __launch_bounds__(256) void k_finalize(const float* __restrict__ P,
                                                  const int* __restrict__ Y,
                                                  const unsigned* __restrict__ uniq,
                                                  float* __restrict__ stats6) {
  __shared__ float whist[4 * NC];
  const int b = blockIdx.x;          // 64 blocks == batches
  const int t = threadIdx.x;

  int cnt[NC];
#pragma unroll
  for (int c = 0; c < NC; ++c) cnt[c] = 0;
#pragma unroll
  for (int i = 0; i < 16; ++i) {
    const int y = Y[b * NN + 256 * i + t];
#pragma unroll
    for (int c = 0; c < NC; ++c) cnt[c] += (y == c) ? 1 : 0;
  }
#pragma unroll
  for (int c = 0; c < NC; ++c) {
    int v = cnt[c];
    for (int off = 32; off; off >>= 1) v += __shfl_down(v, off, 64);
    cnt[c] = v;
  }
  if ((t & 63) == 0) {
#pragma unroll
    for (int c = 0; c < NC; ++c) whist[(t >> 6) * NC + c] = (float)cnt[c];
  }
  __syncthreads();

  const int f = t;
  const int col = b * 256 + f;
  float acc[16];
#pragma unroll
  for (int i = 0; i < 16; ++i) acc[i] = 0.f;
  for (int sp = 0; sp < NSPLIT; ++sp) {
    const float4* p4 = (const float4*)(P + ((size_t)(b * NSPLIT + sp) * NF + f) * 16);
    float4 A = p4[0], B4 = p4[1], C4 = p4[2], D4 = p4[3];
    acc[0] += A.x; acc[1] += A.y; acc[2] += A.z; acc[3] = fmaxf(acc[3], A.w);
    acc[4] += B4.x; acc[5] += B4.y; acc[6] += B4.z; acc[7] += B4.w;
    acc[8] += C4.x; acc[9] += C4.y; acc[10] += C4.z; acc[11] += C4.w;
    acc[12] += D4.x; acc[13] += D4.y; acc[14] += D4.z;
  }
  const float invN = 1.f / (float)NN;
  const float mean = acc[0] * invN;
  float var = acc[1] * invN - mean * mean;
  if (var < 0.f) var = 0.f;
  const float meanabs = acc[2] * invN;
  const float maxabs = acc[3];
  const float miss = acc[4] * invN;
  const float uratio = (float)uniq[col] * invN;
  float btw = 0.f;
#pragma unroll
  for (int c = 0; c < NC; ++c) {
    const float cntc = whist[c] + whist[NC + c] + whist[2 * NC + c] + whist[3 * NC + c];
    const float m = acc[5 + c] / fmaxf(cntc, 1.f);
    const float d = m - mean;
    btw = fmaf(cntc * d, d, btw);
  }
  btw *= invN;  // counts.sum() == N
  const float target = btw / fmaxf(var, 1e-6f);
  float st[6] = {target, miss, uratio, var, meanabs, maxabs};
#pragma unroll
  for (int i = 0; i < 6; ++i)
    if (!(fabsf(st[i]) <= 3.4028235e38f)) st[i] = 0.f;  // nan_to_num(nan/±inf → 0)
#pragma unroll
  for (int i = 0; i < 6; ++i) stats6[(size_t)col * 6 + i] = st[i];
}

// ---------------------------------------------------------------- K4: MLP  gelu(stats@W1+b1)@W2+b2
__global__ __launch_bounds__(256) void k_mlp(const float* __restrict__ stats6,
                                             const float* __restrict__ W1,
                                             const float* __restrict__ b1,
                                             const float* __restrict__ W2,
                                             const float* __restrict__ b2,
                                             float* __restrict__ out) {
  __shared__ float w1s[6 * 64];
  __shared__ float b1s[64];
  __shared__ float w2s[64 * 128];
  __shared__ float b2s[128];
  __shared__ float sts[32 * 6];
  __shared__ float hs[64 * 36];  // pitch 36 keeps float4 reads 16B-aligned
  const int t = threadIdx.x;
  const int cb0 = blockIdx.x * 32;
  for (int i = t; i < 96; i += 256) ((float4*)w1s)[i] = ((const float4*)W1)[i];
  if (t < 64) b1s[t] = b1[t];
  for (int i = t; i < 2048; i += 256) ((float4*)w2s)[i] = ((const float4*)W2)[i];
  if (t < 128) b2s[t] = b2[t];
  if (t < 48) ((float4*)sts)[t] = ((const float4*)(stats6 + (size_t)cb0 * 6))[t];
  __syncthreads();

  const int k = t & 63, cg = t >> 6;
#pragma unroll
  for (int cc = 0; cc < 8; ++cc) {
    const int col = cg + 4 * cc;
    float pre = b1s[k];
#pragma unroll
    for (int s = 0; s < 6; ++s) pre = fmaf(sts[col * 6 + s], w1s[s * 64 + k], pre);
    const float h = 0.5f * pre * (1.f + erff(pre * 0.70710678118654752f));  // exact gelu
    hs[k * 36 + col] = h;
  }
  __syncthreads();

  const int j4 = (t & 31) * 4, c4 = (t >> 5) * 4;
  float4 a[4];
  const float4 bj = *(const float4*)&b2s[j4];
  a[0] = bj; a[1] = bj; a[2] = bj; a[3] = bj;
  for (int kk = 0; kk < 64; ++kk) {
    const float4 wv = *(const float4*)&w2s[kk * 128 + j4];
    const float4 hv = *(const float4*)&hs[kk * 36 + c4];
    const float hc[4] = {hv.x, hv.y, hv.z, hv.w};
#pragma unroll
    for (int ci = 0; ci < 4; ++ci) {
      a[ci].x = fmaf(hc[ci], wv.x, a[ci].x);
      a[ci].y = fmaf(hc[ci], wv.y, a[ci].y);
      a[ci].z = fmaf(hc[ci], wv.z, a[ci].z);
      a[ci].w = fmaf(hc[ci], wv.w, a[ci].w);
    }
  }
#pragma unroll
  for (int ci = 0; ci < 4; ++ci) {
    const int col = cb0 + c4 + ci;
    *(float4*)&out[(size_t)col * 128 + j4] = a[ci];
  }
}

// ---------------------------------------------------------------- launch
extern "C" void kernel_launch(void* const* d_in, const int* in_sizes, int n_in,
                              void* d_out, int out_size, void* d_ws, size_t ws_size,
                              hipStream_t stream) {
  const float* X = (const float*)d_in[0];
  const int* Y = (const int*)d_in[1];
  const float* W1 = (const float*)d_in[2];
  const float* b1 = (const float*)d_in[3];
  const float* W2 = (const float*)d_in[4];
  const float* b2 = (const float*)d_in[5];
  float* out = (float*)d_out;

  // workspace layout (~302.4 MiB)
  char* w = (char*)d_ws;
  unsigned* XT = (unsigned*)w;                          // 268,435,456 B  [B,F,N] cleaned bit patterns
  float* P = (float*)(w + 268435456ull);                //  33,554,432 B  partial stats [B,S,F,16]
  float* stats6 = (float*)(w + 301989888ull);           //     393,216 B  [16384,6]
  unsigned* uniq = (unsigned*)(w + 302383104ull);       //      65,536 B  [16384]

  k_stats<<<NB * NSPLIT, 256, 0, stream>>>(X, Y, XT, P);
  k_uniq<<<NB * NF, 256, 0, stream>>>(XT, uniq);
  k_finalize<<<NB, 256, 0, stream>>>(P, Y, uniq, stats6);
  k_mlp<<<512, 256, 0, stream>>>(stats6, W1, b1, W2, b2, out);
}